// Round 2
// baseline (549.329 us; speedup 1.0000x reference)
//
#include <hip/hip_runtime.h>
#include <hip/hip_bf16.h>

#define N_NODES 50000
#define N_EDGES 800000
#define DIM 128
#define N_GRAPHS 256
#define N_CLASSES 16
#define BN_EPS 1e-5f
#define SCAN_B 256
#define NBLK ((N_NODES + SCAN_B - 1) / SCAN_B)   // 196

// ---------------- setup kernels ----------------

__global__ void k_init(int* degcnt, float* gsum, float* counts) {
    int i = blockIdx.x * blockDim.x + threadIdx.x;
    if (i < N_NODES) degcnt[i] = 0;
    if (i < N_GRAPHS * DIM) gsum[i] = 0.f;
    if (i < N_GRAPHS) counts[i] = 0.f;
}

__global__ void k_count(const int* __restrict__ ei, int* __restrict__ degcnt) {
    int e = blockIdx.x * blockDim.x + threadIdx.x;
    if (e < N_EDGES) atomicAdd(&degcnt[ei[N_EDGES + e]], 1);
}

__global__ void k_dinv(const int* __restrict__ degcnt, float* __restrict__ dinv) {
    int v = blockIdx.x * blockDim.x + threadIdx.x;
    if (v < N_NODES) dinv[v] = rsqrtf((float)(degcnt[v] + 1));  // +1 self-loop, always >=1
}

__global__ void k_blocksum(const int* __restrict__ cnt, int* __restrict__ bsum) {
    __shared__ int buf[SCAN_B];
    int idx = blockIdx.x * SCAN_B + threadIdx.x;
    buf[threadIdx.x] = (idx < N_NODES) ? cnt[idx] : 0;
    __syncthreads();
    for (int off = SCAN_B / 2; off > 0; off >>= 1) {
        if (threadIdx.x < off) buf[threadIdx.x] += buf[threadIdx.x + off];
        __syncthreads();
    }
    if (threadIdx.x == 0) bsum[blockIdx.x] = buf[0];
}

__global__ void k_scanbsum(int* __restrict__ bsum, int* __restrict__ rowptr) {
    // single block; NBLK (=196) <= 256
    __shared__ int buf[SCAN_B];
    int t = threadIdx.x;
    int v = (t < NBLK) ? bsum[t] : 0;
    buf[t] = v;
    __syncthreads();
    for (int off = 1; off < SCAN_B; off <<= 1) {
        int x = buf[t];
        int add = (t >= off) ? buf[t - off] : 0;
        __syncthreads();
        buf[t] = x + add;
        __syncthreads();
    }
    int incl = buf[t];
    if (t < NBLK) bsum[t] = incl - v;      // exclusive block offsets
    if (t == SCAN_B - 1) rowptr[N_NODES] = incl;  // total = E
}

__global__ void k_scanfinal(const int* __restrict__ cnt, const int* __restrict__ bsum,
                            int* __restrict__ rowptr, int* __restrict__ fillpos) {
    __shared__ int buf[SCAN_B];
    int t = threadIdx.x;
    int idx = blockIdx.x * SCAN_B + t;
    int v = (idx < N_NODES) ? cnt[idx] : 0;
    buf[t] = v;
    __syncthreads();
    for (int off = 1; off < SCAN_B; off <<= 1) {
        int x = buf[t];
        int add = (t >= off) ? buf[t - off] : 0;
        __syncthreads();
        buf[t] = x + add;
        __syncthreads();
    }
    if (idx < N_NODES) {
        int r = bsum[blockIdx.x] + buf[t] - v;   // exclusive
        rowptr[idx] = r;
        fillpos[idx] = r;
    }
}

__global__ void k_fill(const int* __restrict__ ei, int* __restrict__ fillpos,
                       int* __restrict__ colidx) {
    int e = blockIdx.x * blockDim.x + threadIdx.x;
    if (e < N_EDGES) {
        int d = ei[N_EDGES + e];
        int s = ei[e];
        int pos = atomicAdd(&fillpos[d], 1);
        colidx[pos] = s;
    }
}

__global__ void k_bnfold(const float* __restrict__ b0, const float* __restrict__ bk,
                         const float* __restrict__ gamma, const float* __restrict__ beta,
                         const float* __restrict__ mean, const float* __restrict__ var,
                         float* __restrict__ alphaL, float* __restrict__ betaL) {
    int i = blockIdx.x * blockDim.x + threadIdx.x;
    if (i >= 3 * DIM) return;
    int l = i / DIM, c = i % DIM;
    float bias = (l == 0) ? b0[c] : bk[(l - 1) * DIM + c];
    float a = gamma[i] * rsqrtf(var[i] + BN_EPS);
    alphaL[i] = a;
    betaL[i] = (bias - mean[i]) * a + beta[i];
}

// ---------------- GEMM: out[r][c] = (A @ W)[r][c] * dinv[r] ----------------
// 64 rows/block, 256 threads; thread owns 4 rows x 8 cols.

#define GR 64
__global__ __launch_bounds__(256) void k_gemm_scale(const float* __restrict__ A,
                                                    const float* __restrict__ W,
                                                    const float* __restrict__ dinv,
                                                    float* __restrict__ out) {
    __shared__ float Alds[GR][DIM + 1];   // pad -> 2-way max bank aliasing (free)
    int t = threadIdx.x;
    int base = blockIdx.x * GR;

    #pragma unroll
    for (int it = 0; it < 8; ++it) {
        int q = it * 256 + t;            // float4 index, 2048 total
        int row = q >> 5;                // 32 float4 per row
        int c4 = (q & 31) << 2;
        int gr = base + row;
        float4 v = make_float4(0.f, 0.f, 0.f, 0.f);
        if (gr < N_NODES) v = *(const float4*)&A[(size_t)gr * DIM + c4];
        Alds[row][c4 + 0] = v.x; Alds[row][c4 + 1] = v.y;
        Alds[row][c4 + 2] = v.z; Alds[row][c4 + 3] = v.w;
    }
    __syncthreads();

    int ir = t >> 4, ic = t & 15;
    int r0 = ir * 4, c0 = ic * 8;
    float acc[4][8];
    #pragma unroll
    for (int i = 0; i < 4; ++i)
        #pragma unroll
        for (int j = 0; j < 8; ++j) acc[i][j] = 0.f;

    for (int k = 0; k < DIM; ++k) {
        float4 w0 = *(const float4*)&W[k * DIM + c0];
        float4 w1 = *(const float4*)&W[k * DIM + c0 + 4];
        float wv[8] = {w0.x, w0.y, w0.z, w0.w, w1.x, w1.y, w1.z, w1.w};
        float av[4];
        #pragma unroll
        for (int i = 0; i < 4; ++i) av[i] = Alds[r0 + i][k];
        #pragma unroll
        for (int i = 0; i < 4; ++i)
            #pragma unroll
            for (int j = 0; j < 8; ++j) acc[i][j] = fmaf(av[i], wv[j], acc[i][j]);
    }

    #pragma unroll
    for (int i = 0; i < 4; ++i) {
        int gr = base + r0 + i;
        if (gr < N_NODES) {
            float s = dinv[gr];
            float4 o0 = make_float4(acc[i][0] * s, acc[i][1] * s, acc[i][2] * s, acc[i][3] * s);
            float4 o1 = make_float4(acc[i][4] * s, acc[i][5] * s, acc[i][6] * s, acc[i][7] * s);
            *(float4*)&out[(size_t)gr * DIM + c0] = o0;
            *(float4*)&out[(size_t)gr * DIM + c0 + 4] = o1;
        }
    }
}

// ---------------- aggregate: out[v] = relu( (sum_{u->v} hs[u] + hs[v]) * dinv[v] * alpha + beta ) ----------------
// one wave per node, float2 per lane (64*8B = full 512B row)

__global__ __launch_bounds__(256) void k_aggregate(const float* __restrict__ hs,
                                                   const int* __restrict__ rowptr,
                                                   const int* __restrict__ colidx,
                                                   const float* __restrict__ dinv,
                                                   const float* __restrict__ alpha,
                                                   const float* __restrict__ beta,
                                                   float* __restrict__ out) {
    int v = blockIdx.x * 4 + (threadIdx.x >> 6);
    if (v >= N_NODES) return;
    int lane = threadIdx.x & 63;
    int c = 2 * lane;

    float2 self = *(const float2*)&hs[(size_t)v * DIM + c];
    float ax = self.x, ay = self.y;

    int beg = rowptr[v], end = rowptr[v + 1];
    int i = beg;
    for (; i + 4 <= end; i += 4) {
        int u0 = colidx[i], u1 = colidx[i + 1], u2 = colidx[i + 2], u3 = colidx[i + 3];
        float2 b0 = *(const float2*)&hs[(size_t)u0 * DIM + c];
        float2 b1 = *(const float2*)&hs[(size_t)u1 * DIM + c];
        float2 b2 = *(const float2*)&hs[(size_t)u2 * DIM + c];
        float2 b3 = *(const float2*)&hs[(size_t)u3 * DIM + c];
        ax += b0.x + b1.x + b2.x + b3.x;
        ay += b0.y + b1.y + b2.y + b3.y;
    }
    for (; i < end; ++i) {
        int u = colidx[i];
        float2 b = *(const float2*)&hs[(size_t)u * DIM + c];
        ax += b.x; ay += b.y;
    }

    float dv = dinv[v];
    float2 al = *(const float2*)&alpha[c];
    float2 be = *(const float2*)&beta[c];
    float ox = fmaxf(fmaf(ax * dv, al.x, be.x), 0.f);
    float oy = fmaxf(fmaf(ay * dv, al.y, be.y), 0.f);
    *(float2*)&out[(size_t)v * DIM + c] = make_float2(ox, oy);
}

// ---------------- pooling: sorted-batch run-length accumulate, flush atomics ----------------

#define POOL_CH 128
__global__ __launch_bounds__(256) void k_pool(const float* __restrict__ h,
                                              const int* __restrict__ batch,
                                              float* __restrict__ gsum,
                                              float* __restrict__ counts) {
    int wv = blockIdx.x * 4 + (threadIdx.x >> 6);
    int n0 = wv * POOL_CH;
    if (n0 >= N_NODES) return;
    int n1 = min(n0 + POOL_CH, N_NODES);
    int lane = threadIdx.x & 63;
    int c = 2 * lane;

    float ax = 0.f, ay = 0.f;
    int cnt = 0;
    int gcur = batch[n0];
    for (int n = n0; n < n1; ++n) {
        int g = batch[n];
        if (g != gcur) {
            atomicAdd(&gsum[gcur * DIM + c], ax);
            atomicAdd(&gsum[gcur * DIM + c + 1], ay);
            if (lane == 0) atomicAdd(&counts[gcur], (float)cnt);
            ax = ay = 0.f; cnt = 0; gcur = g;
        }
        float2 hv = *(const float2*)&h[(size_t)n * DIM + c];
        ax += hv.x; ay += hv.y; cnt++;
    }
    atomicAdd(&gsum[gcur * DIM + c], ax);
    atomicAdd(&gsum[gcur * DIM + c + 1], ay);
    if (lane == 0) atomicAdd(&counts[gcur], (float)cnt);
}

// ---------------- head: per-graph MLP ----------------

__global__ __launch_bounds__(128) void k_head(const float* __restrict__ gsum,
                                              const float* __restrict__ counts,
                                              const float* __restrict__ scalar,
                                              const float* __restrict__ Ws, const float* __restrict__ bs,
                                              const float* __restrict__ Wc1, const float* __restrict__ bc1,
                                              const float* __restrict__ Wc2, const float* __restrict__ bc2,
                                              float* __restrict__ out) {
    __shared__ float z[DIM + DIM / 2];   // 192
    __shared__ float z1[DIM];
    int g = blockIdx.x, t = threadIdx.x;

    float cntv = fmaxf(counts[g], 1.0f);
    z[t] = gsum[g * DIM + t] / cntv;
    if (t < DIM / 2) {
        float s = bs[t];
        #pragma unroll
        for (int i = 0; i < 8; ++i) s = fmaf(scalar[g * 8 + i], Ws[i * (DIM / 2) + t], s);
        z[DIM + t] = fmaxf(s, 0.f);
    }
    __syncthreads();

    {
        float s = bc1[t];
        for (int i = 0; i < DIM + DIM / 2; ++i) s = fmaf(z[i], Wc1[i * DIM + t], s);
        z1[t] = fmaxf(s, 0.f);
    }
    __syncthreads();

    if (t < N_CLASSES) {
        float s = bc2[t];
        for (int i = 0; i < DIM; ++i) s = fmaf(z1[i], Wc2[i * N_CLASSES + t], s);
        out[g * N_CLASSES + t] = s;
    }
}

// ---------------- launch ----------------

extern "C" void kernel_launch(void* const* d_in, const int* in_sizes, int n_in,
                              void* d_out, int out_size, void* d_ws, size_t ws_size,
                              hipStream_t stream) {
    const float* x      = (const float*)d_in[0];
    const int*   ei     = (const int*)d_in[1];
    const int*   batch  = (const int*)d_in[2];
    const float* scalar = (const float*)d_in[3];
    const float* W0     = (const float*)d_in[4];
    const float* b0     = (const float*)d_in[5];
    const float* Wk     = (const float*)d_in[6];
    const float* bk     = (const float*)d_in[7];
    const float* gamma  = (const float*)d_in[8];
    const float* beta   = (const float*)d_in[9];
    const float* mean   = (const float*)d_in[10];
    const float* var    = (const float*)d_in[11];
    const float* Ws     = (const float*)d_in[12];
    const float* bs     = (const float*)d_in[13];
    const float* Wc1    = (const float*)d_in[14];
    const float* bc1    = (const float*)d_in[15];
    const float* Wc2    = (const float*)d_in[16];
    const float* bc2    = (const float*)d_in[17];
    float* out = (float*)d_out;

    char* p = (char*)d_ws;
    auto alloc = [&](size_t bytes) -> void* {
        void* r = (void*)p;
        p += (bytes + 255) & ~(size_t)255;
        return r;
    };
    float* dinv    = (float*)alloc((size_t)N_NODES * 4);
    int*   degcnt  = (int*)  alloc((size_t)N_NODES * 4);
    int*   rowptr  = (int*)  alloc(((size_t)N_NODES + 1) * 4);
    int*   fillpos = (int*)  alloc((size_t)N_NODES * 4);
    int*   bsum    = (int*)  alloc(1024);
    int*   colidx  = (int*)  alloc((size_t)N_EDGES * 4);
    float* alphaL  = (float*)alloc(3 * DIM * 4);
    float* betaL   = (float*)alloc(3 * DIM * 4);
    float* gsum    = (float*)alloc((size_t)N_GRAPHS * DIM * 4);
    float* counts  = (float*)alloc((size_t)N_GRAPHS * 4);
    float* bufA    = (float*)alloc((size_t)N_NODES * DIM * 4);
    float* bufB    = (float*)alloc((size_t)N_NODES * DIM * 4);

    const int edgeBlocks = (N_EDGES + 255) / 256;     // 3125
    const int nodeBlocks = (N_NODES + 255) / 256;     // 196
    const int gemmBlocks = (N_NODES + GR - 1) / GR;   // 782
    const int aggBlocks  = (N_NODES + 3) / 4;         // 12500
    const int poolWaves  = (N_NODES + POOL_CH - 1) / POOL_CH;  // 391
    const int poolBlocks = (poolWaves + 3) / 4;       // 98

    k_init<<<nodeBlocks, 256, 0, stream>>>(degcnt, gsum, counts);
    k_count<<<edgeBlocks, 256, 0, stream>>>(ei, degcnt);
    k_dinv<<<nodeBlocks, 256, 0, stream>>>(degcnt, dinv);
    k_blocksum<<<NBLK, SCAN_B, 0, stream>>>(degcnt, bsum);
    k_scanbsum<<<1, SCAN_B, 0, stream>>>(bsum, rowptr);
    k_scanfinal<<<NBLK, SCAN_B, 0, stream>>>(degcnt, bsum, rowptr, fillpos);
    k_fill<<<edgeBlocks, 256, 0, stream>>>(ei, fillpos, colidx);
    k_bnfold<<<2, 256, 0, stream>>>(b0, bk, gamma, beta, mean, var, alphaL, betaL);

    // layer 1
    k_gemm_scale<<<gemmBlocks, 256, 0, stream>>>(x, W0, dinv, bufB);
    k_aggregate<<<aggBlocks, 256, 0, stream>>>(bufB, rowptr, colidx, dinv,
                                               alphaL + 0 * DIM, betaL + 0 * DIM, bufA);
    // layer 2
    k_gemm_scale<<<gemmBlocks, 256, 0, stream>>>(bufA, Wk, dinv, bufB);
    k_aggregate<<<aggBlocks, 256, 0, stream>>>(bufB, rowptr, colidx, dinv,
                                               alphaL + 1 * DIM, betaL + 1 * DIM, bufA);
    // layer 3
    k_gemm_scale<<<gemmBlocks, 256, 0, stream>>>(bufA, Wk + DIM * DIM, dinv, bufB);
    k_aggregate<<<aggBlocks, 256, 0, stream>>>(bufB, rowptr, colidx, dinv,
                                               alphaL + 2 * DIM, betaL + 2 * DIM, bufA);

    k_pool<<<poolBlocks, 256, 0, stream>>>(bufA, batch, gsum, counts);
    k_head<<<N_GRAPHS, 128, 0, stream>>>(gsum, counts, scalar, Ws, bs, Wc1, bc1, Wc2, bc2, out);
}

// Round 3
// 485.095 us; speedup vs baseline: 1.1324x; 1.1324x over previous
//
#include <hip/hip_runtime.h>
#include <hip/hip_bf16.h>

#define N_NODES 50000
#define N_EDGES 800000
#define DIM 128
#define N_GRAPHS 256
#define N_CLASSES 16
#define BN_EPS 1e-5f
#define SCAN_B 256
#define NBLK ((N_NODES + SCAN_B - 1) / SCAN_B)   // 196

// ---------------- setup kernels ----------------

__global__ void k_init(int* degcnt, float* gsum, float* counts) {
    int i = blockIdx.x * blockDim.x + threadIdx.x;
    if (i < N_NODES) degcnt[i] = 0;
    if (i < N_GRAPHS * DIM) gsum[i] = 0.f;
    if (i < N_GRAPHS) counts[i] = 0.f;
}

__global__ void k_count(const int* __restrict__ ei, int* __restrict__ degcnt) {
    int e = blockIdx.x * blockDim.x + threadIdx.x;
    if (e < N_EDGES) atomicAdd(&degcnt[ei[N_EDGES + e]], 1);
}

__global__ void k_dinv(const int* __restrict__ degcnt, float* __restrict__ dinv) {
    int v = blockIdx.x * blockDim.x + threadIdx.x;
    if (v < N_NODES) dinv[v] = rsqrtf((float)(degcnt[v] + 1));  // +1 self-loop, always >=1
}

__global__ void k_blocksum(const int* __restrict__ cnt, int* __restrict__ bsum) {
    __shared__ int buf[SCAN_B];
    int idx = blockIdx.x * SCAN_B + threadIdx.x;
    buf[threadIdx.x] = (idx < N_NODES) ? cnt[idx] : 0;
    __syncthreads();
    for (int off = SCAN_B / 2; off > 0; off >>= 1) {
        if (threadIdx.x < off) buf[threadIdx.x] += buf[threadIdx.x + off];
        __syncthreads();
    }
    if (threadIdx.x == 0) bsum[blockIdx.x] = buf[0];
}

__global__ void k_scanbsum(int* __restrict__ bsum, int* __restrict__ rowptr) {
    // single block; NBLK (=196) <= 256
    __shared__ int buf[SCAN_B];
    int t = threadIdx.x;
    int v = (t < NBLK) ? bsum[t] : 0;
    buf[t] = v;
    __syncthreads();
    for (int off = 1; off < SCAN_B; off <<= 1) {
        int x = buf[t];
        int add = (t >= off) ? buf[t - off] : 0;
        __syncthreads();
        buf[t] = x + add;
        __syncthreads();
    }
    int incl = buf[t];
    if (t < NBLK) bsum[t] = incl - v;      // exclusive block offsets
    if (t == SCAN_B - 1) rowptr[N_NODES] = incl;  // total = E
}

__global__ void k_scanfinal(const int* __restrict__ cnt, const int* __restrict__ bsum,
                            int* __restrict__ rowptr, int* __restrict__ fillpos) {
    __shared__ int buf[SCAN_B];
    int t = threadIdx.x;
    int idx = blockIdx.x * SCAN_B + t;
    int v = (idx < N_NODES) ? cnt[idx] : 0;
    buf[t] = v;
    __syncthreads();
    for (int off = 1; off < SCAN_B; off <<= 1) {
        int x = buf[t];
        int add = (t >= off) ? buf[t - off] : 0;
        __syncthreads();
        buf[t] = x + add;
        __syncthreads();
    }
    if (idx < N_NODES) {
        int r = bsum[blockIdx.x] + buf[t] - v;   // exclusive
        rowptr[idx] = r;
        fillpos[idx] = r;
    }
}

__global__ void k_fill(const int* __restrict__ ei, int* __restrict__ fillpos,
                       int* __restrict__ colidx) {
    int e = blockIdx.x * blockDim.x + threadIdx.x;
    if (e < N_EDGES) {
        int d = ei[N_EDGES + e];
        int s = ei[e];
        int pos = atomicAdd(&fillpos[d], 1);
        colidx[pos] = s;
    }
}

__global__ void k_bnfold(const float* __restrict__ b0, const float* __restrict__ bk,
                         const float* __restrict__ gamma, const float* __restrict__ beta,
                         const float* __restrict__ mean, const float* __restrict__ var,
                         float* __restrict__ alphaL, float* __restrict__ betaL) {
    int i = blockIdx.x * blockDim.x + threadIdx.x;
    if (i >= 3 * DIM) return;
    int l = i / DIM, c = i % DIM;
    float bias = (l == 0) ? b0[c] : bk[(l - 1) * DIM + c];
    float a = gamma[i] * rsqrtf(var[i] + BN_EPS);
    alphaL[i] = a;
    betaL[i] = (bias - mean[i]) * a + beta[i];
}

// ---------------- GEMM: out[r][c] = bf16( (A @ W)[r][c] * dinv[r] ) ----------------
// 64 rows/block, 256 threads; thread owns 4 rows x 8 cols. Output stored bf16
// (gather operand for k_aggregate) -> halves gather/store bytes.

__device__ __forceinline__ ushort f32_to_bf16_rne(float f) {
    uint b = __float_as_uint(f);
    uint r = (b + 0x7fffu + ((b >> 16) & 1u)) >> 16;
    return (ushort)r;
}

#define GR 64
__global__ __launch_bounds__(256) void k_gemm_scale(const float* __restrict__ A,
                                                    const float* __restrict__ W,
                                                    const float* __restrict__ dinv,
                                                    ushort* __restrict__ out) {
    __shared__ float Alds[GR][DIM + 1];   // pad -> 2-way max bank aliasing (free)
    int t = threadIdx.x;
    int base = blockIdx.x * GR;

    #pragma unroll
    for (int it = 0; it < 8; ++it) {
        int q = it * 256 + t;            // float4 index, 2048 total
        int row = q >> 5;                // 32 float4 per row
        int c4 = (q & 31) << 2;
        int gr = base + row;
        float4 v = make_float4(0.f, 0.f, 0.f, 0.f);
        if (gr < N_NODES) v = *(const float4*)&A[(size_t)gr * DIM + c4];
        Alds[row][c4 + 0] = v.x; Alds[row][c4 + 1] = v.y;
        Alds[row][c4 + 2] = v.z; Alds[row][c4 + 3] = v.w;
    }
    __syncthreads();

    int ir = t >> 4, ic = t & 15;
    int r0 = ir * 4, c0 = ic * 8;
    float acc[4][8];
    #pragma unroll
    for (int i = 0; i < 4; ++i)
        #pragma unroll
        for (int j = 0; j < 8; ++j) acc[i][j] = 0.f;

    for (int k = 0; k < DIM; ++k) {
        float4 w0 = *(const float4*)&W[k * DIM + c0];
        float4 w1 = *(const float4*)&W[k * DIM + c0 + 4];
        float wv[8] = {w0.x, w0.y, w0.z, w0.w, w1.x, w1.y, w1.z, w1.w};
        float av[4];
        #pragma unroll
        for (int i = 0; i < 4; ++i) av[i] = Alds[r0 + i][k];
        #pragma unroll
        for (int i = 0; i < 4; ++i)
            #pragma unroll
            for (int j = 0; j < 8; ++j) acc[i][j] = fmaf(av[i], wv[j], acc[i][j]);
    }

    #pragma unroll
    for (int i = 0; i < 4; ++i) {
        int gr = base + r0 + i;
        if (gr < N_NODES) {
            float s = dinv[gr];
            alignas(16) ushort pk[8];
            #pragma unroll
            for (int j = 0; j < 8; ++j) pk[j] = f32_to_bf16_rne(acc[i][j] * s);
            *(uint4*)&out[(size_t)gr * DIM + c0] = *(const uint4*)pk;
        }
    }
}

// ---------------- aggregate ----------------
// out[v] = relu( (sum_{u->v} hs[u] + hs[v]) * dinv[v] * alpha + beta )
// hs is bf16 [N][128]; one wave per node, one uint (2 bf16) per lane = 256B row.
// Accumulation in fp32.

__device__ __forceinline__ float bfx(uint r) { return __uint_as_float(r << 16); }
__device__ __forceinline__ float bfy(uint r) { return __uint_as_float(r & 0xffff0000u); }

__global__ __launch_bounds__(256) void k_aggregate(const ushort* __restrict__ hs,
                                                   const int* __restrict__ rowptr,
                                                   const int* __restrict__ colidx,
                                                   const float* __restrict__ dinv,
                                                   const float* __restrict__ alpha,
                                                   const float* __restrict__ beta,
                                                   float* __restrict__ out) {
    int v = blockIdx.x * 4 + (threadIdx.x >> 6);
    if (v >= N_NODES) return;
    int lane = threadIdx.x & 63;
    int c = 2 * lane;

    uint selfr = *(const uint*)&hs[(size_t)v * DIM + c];
    float ax = bfx(selfr), ay = bfy(selfr);

    int beg = rowptr[v], end = rowptr[v + 1];
    int i = beg;
    for (; i + 4 <= end; i += 4) {
        int u0 = colidx[i], u1 = colidx[i + 1], u2 = colidx[i + 2], u3 = colidx[i + 3];
        uint b0 = *(const uint*)&hs[(size_t)u0 * DIM + c];
        uint b1 = *(const uint*)&hs[(size_t)u1 * DIM + c];
        uint b2 = *(const uint*)&hs[(size_t)u2 * DIM + c];
        uint b3 = *(const uint*)&hs[(size_t)u3 * DIM + c];
        ax += bfx(b0) + bfx(b1) + bfx(b2) + bfx(b3);
        ay += bfy(b0) + bfy(b1) + bfy(b2) + bfy(b3);
    }
    for (; i < end; ++i) {
        int u = colidx[i];
        uint b = *(const uint*)&hs[(size_t)u * DIM + c];
        ax += bfx(b); ay += bfy(b);
    }

    float dv = dinv[v];
    float2 al = *(const float2*)&alpha[c];
    float2 be = *(const float2*)&beta[c];
    float ox = fmaxf(fmaf(ax * dv, al.x, be.x), 0.f);
    float oy = fmaxf(fmaf(ay * dv, al.y, be.y), 0.f);
    *(float2*)&out[(size_t)v * DIM + c] = make_float2(ox, oy);
}

// ---------------- pooling: sorted-batch run-length accumulate, flush atomics ----------------

#define POOL_CH 128
__global__ __launch_bounds__(256) void k_pool(const float* __restrict__ h,
                                              const int* __restrict__ batch,
                                              float* __restrict__ gsum,
                                              float* __restrict__ counts) {
    int wv = blockIdx.x * 4 + (threadIdx.x >> 6);
    int n0 = wv * POOL_CH;
    if (n0 >= N_NODES) return;
    int n1 = min(n0 + POOL_CH, N_NODES);
    int lane = threadIdx.x & 63;
    int c = 2 * lane;

    float ax = 0.f, ay = 0.f;
    int cnt = 0;
    int gcur = batch[n0];
    for (int n = n0; n < n1; ++n) {
        int g = batch[n];
        if (g != gcur) {
            atomicAdd(&gsum[gcur * DIM + c], ax);
            atomicAdd(&gsum[gcur * DIM + c + 1], ay);
            if (lane == 0) atomicAdd(&counts[gcur], (float)cnt);
            ax = ay = 0.f; cnt = 0; gcur = g;
        }
        float2 hv = *(const float2*)&h[(size_t)n * DIM + c];
        ax += hv.x; ay += hv.y; cnt++;
    }
    atomicAdd(&gsum[gcur * DIM + c], ax);
    atomicAdd(&gsum[gcur * DIM + c + 1], ay);
    if (lane == 0) atomicAdd(&counts[gcur], (float)cnt);
}

// ---------------- head: per-graph MLP ----------------

__global__ __launch_bounds__(128) void k_head(const float* __restrict__ gsum,
                                              const float* __restrict__ counts,
                                              const float* __restrict__ scalar,
                                              const float* __restrict__ Ws, const float* __restrict__ bs,
                                              const float* __restrict__ Wc1, const float* __restrict__ bc1,
                                              const float* __restrict__ Wc2, const float* __restrict__ bc2,
                                              float* __restrict__ out) {
    __shared__ float z[DIM + DIM / 2];   // 192
    __shared__ float z1[DIM];
    int g = blockIdx.x, t = threadIdx.x;

    float cntv = fmaxf(counts[g], 1.0f);
    z[t] = gsum[g * DIM + t] / cntv;
    if (t < DIM / 2) {
        float s = bs[t];
        #pragma unroll
        for (int i = 0; i < 8; ++i) s = fmaf(scalar[g * 8 + i], Ws[i * (DIM / 2) + t], s);
        z[DIM + t] = fmaxf(s, 0.f);
    }
    __syncthreads();

    {
        float s = bc1[t];
        for (int i = 0; i < DIM + DIM / 2; ++i) s = fmaf(z[i], Wc1[i * DIM + t], s);
        z1[t] = fmaxf(s, 0.f);
    }
    __syncthreads();

    if (t < N_CLASSES) {
        float s = bc2[t];
        for (int i = 0; i < DIM; ++i) s = fmaf(z1[i], Wc2[i * N_CLASSES + t], s);
        out[g * N_CLASSES + t] = s;
    }
}

// ---------------- launch ----------------

extern "C" void kernel_launch(void* const* d_in, const int* in_sizes, int n_in,
                              void* d_out, int out_size, void* d_ws, size_t ws_size,
                              hipStream_t stream) {
    const float* x      = (const float*)d_in[0];
    const int*   ei     = (const int*)d_in[1];
    const int*   batch  = (const int*)d_in[2];
    const float* scalar = (const float*)d_in[3];
    const float* W0     = (const float*)d_in[4];
    const float* b0     = (const float*)d_in[5];
    const float* Wk     = (const float*)d_in[6];
    const float* bk     = (const float*)d_in[7];
    const float* gamma  = (const float*)d_in[8];
    const float* beta   = (const float*)d_in[9];
    const float* mean   = (const float*)d_in[10];
    const float* var    = (const float*)d_in[11];
    const float* Ws     = (const float*)d_in[12];
    const float* bs     = (const float*)d_in[13];
    const float* Wc1    = (const float*)d_in[14];
    const float* bc1    = (const float*)d_in[15];
    const float* Wc2    = (const float*)d_in[16];
    const float* bc2    = (const float*)d_in[17];
    float* out = (float*)d_out;

    char* p = (char*)d_ws;
    auto alloc = [&](size_t bytes) -> void* {
        void* r = (void*)p;
        p += (bytes + 255) & ~(size_t)255;
        return r;
    };
    float*  dinv    = (float*)alloc((size_t)N_NODES * 4);
    int*    degcnt  = (int*)  alloc((size_t)N_NODES * 4);
    int*    rowptr  = (int*)  alloc(((size_t)N_NODES + 1) * 4);
    int*    fillpos = (int*)  alloc((size_t)N_NODES * 4);
    int*    bsum    = (int*)  alloc(1024);
    int*    colidx  = (int*)  alloc((size_t)N_EDGES * 4);
    float*  alphaL  = (float*)alloc(3 * DIM * 4);
    float*  betaL   = (float*)alloc(3 * DIM * 4);
    float*  gsum    = (float*)alloc((size_t)N_GRAPHS * DIM * 4);
    float*  counts  = (float*)alloc((size_t)N_GRAPHS * 4);
    float*  bufA    = (float*)alloc((size_t)N_NODES * DIM * 4);   // fp32 activations
    ushort* bufH    = (ushort*)alloc((size_t)N_NODES * DIM * 2);  // bf16 hs (gather operand)

    const int edgeBlocks = (N_EDGES + 255) / 256;     // 3125
    const int nodeBlocks = (N_NODES + 255) / 256;     // 196
    const int gemmBlocks = (N_NODES + GR - 1) / GR;   // 782
    const int aggBlocks  = (N_NODES + 3) / 4;         // 12500
    const int poolWaves  = (N_NODES + POOL_CH - 1) / POOL_CH;  // 391
    const int poolBlocks = (poolWaves + 3) / 4;       // 98

    k_init<<<nodeBlocks, 256, 0, stream>>>(degcnt, gsum, counts);
    k_count<<<edgeBlocks, 256, 0, stream>>>(ei, degcnt);
    k_dinv<<<nodeBlocks, 256, 0, stream>>>(degcnt, dinv);
    k_blocksum<<<NBLK, SCAN_B, 0, stream>>>(degcnt, bsum);
    k_scanbsum<<<1, SCAN_B, 0, stream>>>(bsum, rowptr);
    k_scanfinal<<<NBLK, SCAN_B, 0, stream>>>(degcnt, bsum, rowptr, fillpos);
    k_fill<<<edgeBlocks, 256, 0, stream>>>(ei, fillpos, colidx);
    k_bnfold<<<2, 256, 0, stream>>>(b0, bk, gamma, beta, mean, var, alphaL, betaL);

    // layer 1
    k_gemm_scale<<<gemmBlocks, 256, 0, stream>>>(x, W0, dinv, bufH);
    k_aggregate<<<aggBlocks, 256, 0, stream>>>(bufH, rowptr, colidx, dinv,
                                               alphaL + 0 * DIM, betaL + 0 * DIM, bufA);
    // layer 2
    k_gemm_scale<<<gemmBlocks, 256, 0, stream>>>(bufA, Wk, dinv, bufH);
    k_aggregate<<<aggBlocks, 256, 0, stream>>>(bufH, rowptr, colidx, dinv,
                                               alphaL + 1 * DIM, betaL + 1 * DIM, bufA);
    // layer 3
    k_gemm_scale<<<gemmBlocks, 256, 0, stream>>>(bufA, Wk + DIM * DIM, dinv, bufH);
    k_aggregate<<<aggBlocks, 256, 0, stream>>>(bufH, rowptr, colidx, dinv,
                                               alphaL + 2 * DIM, betaL + 2 * DIM, bufA);

    k_pool<<<poolBlocks, 256, 0, stream>>>(bufA, batch, gsum, counts);
    k_head<<<N_GRAPHS, 128, 0, stream>>>(gsum, counts, scalar, Ws, bs, Wc1, bc1, Wc2, bc2, out);
}

// Round 5
// 424.685 us; speedup vs baseline: 1.2935x; 1.1422x over previous
//
#include <hip/hip_runtime.h>
#include <hip/hip_bf16.h>

#define N_NODES 50000
#define N_EDGES 800000
#define DIM 128
#define N_GRAPHS 256
#define N_CLASSES 16
#define BN_EPS 1e-5f
#define SCAN_B 256
#define NBLK ((N_NODES + SCAN_B - 1) / SCAN_B)   // 196

typedef unsigned int uint;
typedef unsigned short ushort;
typedef __attribute__((ext_vector_type(8))) short short8;
typedef __attribute__((ext_vector_type(4))) float f32x4;

__device__ __forceinline__ ushort f32_to_bf16_rne(float f) {
    uint b = __float_as_uint(f);
    uint r = (b + 0x7fffu + ((b >> 16) & 1u)) >> 16;
    return (ushort)r;
}
__device__ __forceinline__ float bfx(uint r) { return __uint_as_float(r << 16); }
__device__ __forceinline__ float bfy(uint r) { return __uint_as_float(r & 0xffff0000u); }

// ---------------- setup kernels ----------------

__global__ void k_init(int* degcnt, float* gsum, float* counts) {
    int i = blockIdx.x * blockDim.x + threadIdx.x;
    if (i < N_NODES) degcnt[i] = 0;
    if (i < N_GRAPHS * DIM) gsum[i] = 0.f;
    if (i < N_GRAPHS) counts[i] = 0.f;
}

__global__ void k_count(const int* __restrict__ ei, int* __restrict__ degcnt) {
    int e = blockIdx.x * blockDim.x + threadIdx.x;
    if (e < N_EDGES) atomicAdd(&degcnt[ei[N_EDGES + e]], 1);
}

__global__ void k_dinv(const int* __restrict__ degcnt, float* __restrict__ dinv) {
    int v = blockIdx.x * blockDim.x + threadIdx.x;
    if (v < N_NODES) dinv[v] = rsqrtf((float)(degcnt[v] + 1));  // +1 self-loop
}

__global__ void k_blocksum(const int* __restrict__ cnt, int* __restrict__ bsum) {
    __shared__ int buf[SCAN_B];
    int idx = blockIdx.x * SCAN_B + threadIdx.x;
    buf[threadIdx.x] = (idx < N_NODES) ? cnt[idx] : 0;
    __syncthreads();
    for (int off = SCAN_B / 2; off > 0; off >>= 1) {
        if (threadIdx.x < off) buf[threadIdx.x] += buf[threadIdx.x + off];
        __syncthreads();
    }
    if (threadIdx.x == 0) bsum[blockIdx.x] = buf[0];
}

__global__ void k_scanbsum(int* __restrict__ bsum, int* __restrict__ rowptr) {
    __shared__ int buf[SCAN_B];
    int t = threadIdx.x;
    int v = (t < NBLK) ? bsum[t] : 0;
    buf[t] = v;
    __syncthreads();
    for (int off = 1; off < SCAN_B; off <<= 1) {
        int x = buf[t];
        int add = (t >= off) ? buf[t - off] : 0;
        __syncthreads();
        buf[t] = x + add;
        __syncthreads();
    }
    int incl = buf[t];
    if (t < NBLK) bsum[t] = incl - v;
    if (t == SCAN_B - 1) rowptr[N_NODES] = incl;
}

__global__ void k_scanfinal(const int* __restrict__ cnt, const int* __restrict__ bsum,
                            int* __restrict__ rowptr, int* __restrict__ fillpos) {
    __shared__ int buf[SCAN_B];
    int t = threadIdx.x;
    int idx = blockIdx.x * SCAN_B + t;
    int v = (idx < N_NODES) ? cnt[idx] : 0;
    buf[t] = v;
    __syncthreads();
    for (int off = 1; off < SCAN_B; off <<= 1) {
        int x = buf[t];
        int add = (t >= off) ? buf[t - off] : 0;
        __syncthreads();
        buf[t] = x + add;
        __syncthreads();
    }
    if (idx < N_NODES) {
        int r = bsum[blockIdx.x] + buf[t] - v;
        rowptr[idx] = r;
        fillpos[idx] = r;
    }
}

__global__ void k_fill(const int* __restrict__ ei, int* __restrict__ fillpos,
                       int* __restrict__ colidx) {
    int e = blockIdx.x * blockDim.x + threadIdx.x;
    if (e < N_EDGES) {
        int d = ei[N_EDGES + e];
        int s = ei[e];
        int pos = atomicAdd(&fillpos[d], 1);
        colidx[pos] = s;
    }
}

__global__ void k_bnfold(const float* __restrict__ b0, const float* __restrict__ bk,
                         const float* __restrict__ gamma, const float* __restrict__ beta,
                         const float* __restrict__ mean, const float* __restrict__ var,
                         float* __restrict__ alphaL, float* __restrict__ betaL) {
    int i = blockIdx.x * blockDim.x + threadIdx.x;
    if (i >= 3 * DIM) return;
    int l = i / DIM, c = i % DIM;
    float bias = (l == 0) ? b0[c] : bk[(l - 1) * DIM + c];
    float a = gamma[i] * rsqrtf(var[i] + BN_EPS);
    alphaL[i] = a;
    betaL[i] = (bias - mean[i]) * a + beta[i];
}

// Wt[l][n][k] = W_l[k][n] as bf16 (transposed so MFMA B-frag reads are k-contiguous)
__global__ void k_wconv(const float* __restrict__ W0, const float* __restrict__ Wk,
                        ushort* __restrict__ Wt) {
    int i = blockIdx.x * blockDim.x + threadIdx.x;
    if (i >= 3 * DIM * DIM) return;
    int l = i >> 14, r = i & 16383, k = r >> 7, n = r & 127;
    float v = (l == 0) ? W0[k * DIM + n] : Wk[(l - 1) * DIM * DIM + k * DIM + n];
    Wt[l * DIM * DIM + n * DIM + k] = f32_to_bf16_rne(v);
}

// ---------------- MFMA GEMM: out[r][c] = bf16( (A @ W)[r][c] * dinv[r] ) ----------------
// BM=64 rows/block, 256 threads = 4 waves; wave w owns rows [w*16, w*16+16) x all 128 cols.
// LDS: sA [64][136] bf16 (+8 pad), sW [128][136] bf16 holding W^T rows (sW[n][k]).
// Fragment: one contiguous ds_read_b128 per operand (8 contiguous k per lane,
// same bijection for A and B -> layout-convention invariant).
// D: col=lane&15, row=(lane>>4)*4+reg  [m89-verified].

#define GR 64
#define APITCH 136

union FragU { uint4 u; short8 s; };

__global__ __launch_bounds__(256) void k_gemm_mfma(const ushort* __restrict__ Abf,
                                                   const float* __restrict__ Af32,
                                                   const ushort* __restrict__ Wt,
                                                   const float* __restrict__ dinv,
                                                   ushort* __restrict__ out) {
    __shared__ ushort sA[GR * APITCH];
    __shared__ ushort sW[DIM * APITCH];
    int t = threadIdx.x;
    int base = blockIdx.x * GR;

    // stage W^T: 128 rows x 128 bf16 = 2048 uint4 chunks (16 per row)
    #pragma unroll
    for (int it = 0; it < 8; ++it) {
        int q = it * 256 + t;
        int n = q >> 4, c = q & 15;
        *(uint4*)&sW[n * APITCH + c * 8] = *(const uint4*)&Wt[n * DIM + c * 8];
    }
    // stage A: 64 rows x 128 bf16
    if (Af32) {
        #pragma unroll
        for (int it = 0; it < 8; ++it) {
            int q = it * 256 + t;      // 2048 float4 chunks (32 per row)
            int row = q >> 5, c = q & 31;
            int gr = base + row;
            float4 v = make_float4(0.f, 0.f, 0.f, 0.f);
            if (gr < N_NODES) v = *(const float4*)&Af32[(size_t)gr * DIM + c * 4];
            ushort pk[4] = {f32_to_bf16_rne(v.x), f32_to_bf16_rne(v.y),
                            f32_to_bf16_rne(v.z), f32_to_bf16_rne(v.w)};
            *(uint2*)&sA[row * APITCH + c * 4] = *(const uint2*)pk;
        }
    } else {
        #pragma unroll
        for (int it = 0; it < 4; ++it) {
            int q = it * 256 + t;      // 1024 uint4 chunks (16 per row)
            int row = q >> 4, c = q & 15;
            int gr = base + row;
            uint4 v = make_uint4(0u, 0u, 0u, 0u);
            if (gr < N_NODES) v = *(const uint4*)&Abf[(size_t)gr * DIM + c * 8];
            *(uint4*)&sA[row * APITCH + c * 8] = v;
        }
    }
    __syncthreads();

    int w = t >> 6, lane = t & 63;
    int lm = lane & 15, lg = lane >> 4;

    f32x4 acc[8];
    #pragma unroll
    for (int nt = 0; nt < 8; ++nt) acc[nt] = (f32x4){0.f, 0.f, 0.f, 0.f};

    const ushort* aRow = &sA[(w * 16 + lm) * APITCH];
    #pragma unroll
    for (int kc = 0; kc < 4; ++kc) {
        int ko = kc * 32 + lg * 8;
        FragU au; au.u = *(const uint4*)&aRow[ko];
        #pragma unroll
        for (int nt = 0; nt < 8; ++nt) {
            FragU bu; bu.u = *(const uint4*)&sW[(nt * 16 + lm) * APITCH + ko];
            acc[nt] = __builtin_amdgcn_mfma_f32_16x16x32_bf16(au.s, bu.s, acc[nt], 0, 0, 0);
        }
    }

    int m0 = base + w * 16 + lg * 4;
    float dv[4];
    #pragma unroll
    for (int j = 0; j < 4; ++j) {
        int gr = m0 + j;
        dv[j] = (gr < N_NODES) ? dinv[gr] : 0.f;
    }
    #pragma unroll
    for (int nt = 0; nt < 8; ++nt) {
        int n = nt * 16 + lm;
        #pragma unroll
        for (int j = 0; j < 4; ++j) {
            int gr = m0 + j;
            if (gr < N_NODES)
                out[(size_t)gr * DIM + n] = f32_to_bf16_rne(acc[nt][j] * dv[j]);
        }
    }
}

// ---------------- aggregate ----------------
// out[v] = bf16( relu( (sum_{u->v} hs[u] + hs[v]) * dinv[v] * alpha + beta ) )
// hs bf16 [N][128]; one wave/node, one uint (2 bf16)/lane = 256B row; fp32 accum.

__global__ __launch_bounds__(256) void k_aggregate(const ushort* __restrict__ hs,
                                                   const int* __restrict__ rowptr,
                                                   const int* __restrict__ colidx,
                                                   const float* __restrict__ dinv,
                                                   const float* __restrict__ alpha,
                                                   const float* __restrict__ beta,
                                                   ushort* __restrict__ out) {
    int v = blockIdx.x * 4 + (threadIdx.x >> 6);
    if (v >= N_NODES) return;
    int lane = threadIdx.x & 63;
    int c = 2 * lane;

    uint selfr = *(const uint*)&hs[(size_t)v * DIM + c];
    float ax = bfx(selfr), ay = bfy(selfr);

    int beg = rowptr[v], end = rowptr[v + 1];
    int i = beg;
    for (; i + 4 <= end; i += 4) {
        int u0 = colidx[i], u1 = colidx[i + 1], u2 = colidx[i + 2], u3 = colidx[i + 3];
        uint b0 = *(const uint*)&hs[(size_t)u0 * DIM + c];
        uint b1 = *(const uint*)&hs[(size_t)u1 * DIM + c];
        uint b2 = *(const uint*)&hs[(size_t)u2 * DIM + c];
        uint b3 = *(const uint*)&hs[(size_t)u3 * DIM + c];
        ax += bfx(b0) + bfx(b1) + bfx(b2) + bfx(b3);
        ay += bfy(b0) + bfy(b1) + bfy(b2) + bfy(b3);
    }
    for (; i < end; ++i) {
        int u = colidx[i];
        uint b = *(const uint*)&hs[(size_t)u * DIM + c];
        ax += bfx(b); ay += bfy(b);
    }

    float dvv = dinv[v];
    float2 al = *(const float2*)&alpha[c];
    float2 be = *(const float2*)&beta[c];
    float ox = fmaxf(fmaf(ax * dvv, al.x, be.x), 0.f);
    float oy = fmaxf(fmaf(ay * dvv, al.y, be.y), 0.f);
    uint lo = f32_to_bf16_rne(ox), hi = f32_to_bf16_rne(oy);
    *(uint*)&out[(size_t)v * DIM + c] = lo | (hi << 16);
}

// ---------------- pooling ----------------

#define POOL_CH 128
__global__ __launch_bounds__(256) void k_pool(const ushort* __restrict__ h,
                                              const int* __restrict__ batch,
                                              float* __restrict__ gsum,
                                              float* __restrict__ counts) {
    int wv = blockIdx.x * 4 + (threadIdx.x >> 6);
    int n0 = wv * POOL_CH;
    if (n0 >= N_NODES) return;
    int n1 = min(n0 + POOL_CH, N_NODES);
    int lane = threadIdx.x & 63;
    int c = 2 * lane;

    float ax = 0.f, ay = 0.f;
    int cnt = 0;
    int gcur = batch[n0];
    for (int n = n0; n < n1; ++n) {
        int g = batch[n];
        if (g != gcur) {
            atomicAdd(&gsum[gcur * DIM + c], ax);
            atomicAdd(&gsum[gcur * DIM + c + 1], ay);
            if (lane == 0) atomicAdd(&counts[gcur], (float)cnt);
            ax = ay = 0.f; cnt = 0; gcur = g;
        }
        uint hv = *(const uint*)&h[(size_t)n * DIM + c];
        ax += bfx(hv); ay += bfy(hv); cnt++;
    }
    atomicAdd(&gsum[gcur * DIM + c], ax);
    atomicAdd(&gsum[gcur * DIM + c + 1], ay);
    if (lane == 0) atomicAdd(&counts[gcur], (float)cnt);
}

// ---------------- head: per-graph MLP ----------------

__global__ __launch_bounds__(128) void k_head(const float* __restrict__ gsum,
                                              const float* __restrict__ counts,
                                              const float* __restrict__ scalar,
                                              const float* __restrict__ Ws, const float* __restrict__ bs,
                                              const float* __restrict__ Wc1, const float* __restrict__ bc1,
                                              const float* __restrict__ Wc2, const float* __restrict__ bc2,
                                              float* __restrict__ out) {
    __shared__ float z[DIM + DIM / 2];
    __shared__ float z1[DIM];
    int g = blockIdx.x, t = threadIdx.x;

    float cntv = fmaxf(counts[g], 1.0f);
    z[t] = gsum[g * DIM + t] / cntv;
    if (t < DIM / 2) {
        float s = bs[t];
        #pragma unroll
        for (int i = 0; i < 8; ++i) s = fmaf(scalar[g * 8 + i], Ws[i * (DIM / 2) + t], s);
        z[DIM + t] = fmaxf(s, 0.f);
    }
    __syncthreads();

    {
        float s = bc1[t];
        for (int i = 0; i < DIM + DIM / 2; ++i) s = fmaf(z[i], Wc1[i * DIM + t], s);
        z1[t] = fmaxf(s, 0.f);
    }
    __syncthreads();

    if (t < N_CLASSES) {
        float s = bc2[t];
        for (int i = 0; i < DIM; ++i) s = fmaf(z1[i], Wc2[i * N_CLASSES + t], s);
        out[g * N_CLASSES + t] = s;
    }
}

// ---------------- launch ----------------

extern "C" void kernel_launch(void* const* d_in, const int* in_sizes, int n_in,
                              void* d_out, int out_size, void* d_ws, size_t ws_size,
                              hipStream_t stream) {
    const float* x      = (const float*)d_in[0];
    const int*   ei     = (const int*)d_in[1];
    const int*   batch  = (const int*)d_in[2];
    const float* scalar = (const float*)d_in[3];
    const float* W0     = (const float*)d_in[4];
    const float* b0     = (const float*)d_in[5];
    const float* Wk     = (const float*)d_in[6];
    const float* bk     = (const float*)d_in[7];
    const float* gamma  = (const float*)d_in[8];
    const float* beta   = (const float*)d_in[9];
    const float* mean   = (const float*)d_in[10];
    const float* var    = (const float*)d_in[11];
    const float* Ws     = (const float*)d_in[12];
    const float* bs     = (const float*)d_in[13];
    const float* Wc1    = (const float*)d_in[14];
    const float* bc1    = (const float*)d_in[15];
    const float* Wc2    = (const float*)d_in[16];
    const float* bc2    = (const float*)d_in[17];
    float* out = (float*)d_out;

    char* p = (char*)d_ws;
    auto alloc = [&](size_t bytes) -> void* {
        void* r = (void*)p;
        p += (bytes + 255) & ~(size_t)255;
        return r;
    };
    float*  dinv    = (float*)alloc((size_t)N_NODES * 4);
    int*    degcnt  = (int*)  alloc((size_t)N_NODES * 4);
    int*    rowptr  = (int*)  alloc(((size_t)N_NODES + 1) * 4);
    int*    fillpos = (int*)  alloc((size_t)N_NODES * 4);
    int*    bsum    = (int*)  alloc(1024);
    int*    colidx  = (int*)  alloc((size_t)N_EDGES * 4);
    float*  alphaL  = (float*)alloc(3 * DIM * 4);
    float*  betaL   = (float*)alloc(3 * DIM * 4);
    float*  gsum    = (float*)alloc((size_t)N_GRAPHS * DIM * 4);
    float*  counts  = (float*)alloc((size_t)N_GRAPHS * 4);
    ushort* Wt      = (ushort*)alloc((size_t)3 * DIM * DIM * 2);
    ushort* bufAct  = (ushort*)alloc((size_t)N_NODES * DIM * 2);  // bf16 activations
    ushort* bufH    = (ushort*)alloc((size_t)N_NODES * DIM * 2);  // bf16 hs (gather operand)

    const int edgeBlocks = (N_EDGES + 255) / 256;
    const int nodeBlocks = (N_NODES + 255) / 256;
    const int gemmBlocks = (N_NODES + GR - 1) / GR;   // 782
    const int aggBlocks  = (N_NODES + 3) / 4;
    const int poolWaves  = (N_NODES + POOL_CH - 1) / POOL_CH;
    const int poolBlocks = (poolWaves + 3) / 4;

    k_init<<<nodeBlocks, 256, 0, stream>>>(degcnt, gsum, counts);
    k_count<<<edgeBlocks, 256, 0, stream>>>(ei, degcnt);
    k_dinv<<<nodeBlocks, 256, 0, stream>>>(degcnt, dinv);
    k_blocksum<<<NBLK, SCAN_B, 0, stream>>>(degcnt, bsum);
    k_scanbsum<<<1, SCAN_B, 0, stream>>>(bsum, rowptr);
    k_scanfinal<<<NBLK, SCAN_B, 0, stream>>>(degcnt, bsum, rowptr, fillpos);
    k_fill<<<edgeBlocks, 256, 0, stream>>>(ei, fillpos, colidx);
    k_bnfold<<<2, 256, 0, stream>>>(b0, bk, gamma, beta, mean, var, alphaL, betaL);
    k_wconv<<<192, 256, 0, stream>>>(W0, Wk, Wt);

    // layer 1 (A = x fp32, converted inline during LDS staging)
    k_gemm_mfma<<<gemmBlocks, 256, 0, stream>>>(nullptr, x, Wt, dinv, bufH);
    k_aggregate<<<aggBlocks, 256, 0, stream>>>(bufH, rowptr, colidx, dinv,
                                               alphaL + 0 * DIM, betaL + 0 * DIM, bufAct);
    // layer 2
    k_gemm_mfma<<<gemmBlocks, 256, 0, stream>>>(bufAct, nullptr, Wt + DIM * DIM, dinv, bufH);
    k_aggregate<<<aggBlocks, 256, 0, stream>>>(bufH, rowptr, colidx, dinv,
                                               alphaL + 1 * DIM, betaL + 1 * DIM, bufAct);
    // layer 3
    k_gemm_mfma<<<gemmBlocks, 256, 0, stream>>>(bufAct, nullptr, Wt + 2 * DIM * DIM, dinv, bufH);
    k_aggregate<<<aggBlocks, 256, 0, stream>>>(bufH, rowptr, colidx, dinv,
                                               alphaL + 2 * DIM, betaL + 2 * DIM, bufAct);

    k_pool<<<poolBlocks, 256, 0, stream>>>(bufAct, batch, gsum, counts);
    k_head<<<N_GRAPHS, 128, 0, stream>>>(gsum, counts, scalar, Ws, bs, Wc1, bc1, Wc2, bc2, out);
}